// Round 1
// baseline (575.690 us; speedup 1.0000x reference)
//
#include <hip/hip_runtime.h>

typedef unsigned short ushort_t;
typedef unsigned int uint32;
typedef __attribute__((ext_vector_type(8))) __bf16 bf16x8;
typedef __attribute__((ext_vector_type(4))) float f32x4;
typedef __attribute__((ext_vector_type(4))) unsigned short us4;

#define S_LEN 4096
#define EMB   1024
#define NH    16
#define HD    64
#define FFD   4096

__device__ __forceinline__ ushort_t f2b(float f){
  uint32 u = __builtin_bit_cast(uint32, f);
  u += 0x7fffu + ((u >> 16) & 1u);
  return (ushort_t)(u >> 16);
}

__device__ __forceinline__ void gload_lds16(const void* g, void* l){
  __builtin_amdgcn_global_load_lds((const __attribute__((address_space(1))) void*)g,
                                   (__attribute__((address_space(3))) void*)l,
                                   16, 0, 0);
}

__device__ __forceinline__ f32x4 mfma16(bf16x8 a, bf16x8 b, f32x4 c){
  return __builtin_amdgcn_mfma_f32_16x16x32_bf16(a, b, c, 0, 0, 0);
}

// ---------------------------------------------------------------------------
// GEMM: C[M,N] = A[M,K] @ B + bias, with B given as BT[N,K] (row-major B^T).
// 128x128 tile, BK=32, 4 waves (2x2 of 64x64), m97 structure.
// EPI: 0 = bias -> bf16 out, 1 = bias -> f32 out, 2 = bias+relu -> bf16 out
// ---------------------------------------------------------------------------
template<int EPI>
__global__ __launch_bounds__(256)
void gemm_bt(const ushort_t* __restrict__ A, const ushort_t* __restrict__ BT,
             int M, int N, int K, const float* __restrict__ bias,
             float* __restrict__ outF, ushort_t* __restrict__ outB)
{
  __shared__ __attribute__((aligned(16))) ushort_t As[128 * 32];
  __shared__ __attribute__((aligned(16))) ushort_t Bs[128 * 32];
  const int tid = threadIdx.x;
  const int w = tid >> 6, lane = tid & 63, l16 = lane & 15, lg = lane >> 4;
  const int brow = blockIdx.y * 128, bcol = blockIdx.x * 128;
  const int wr = (w >> 1) * 64, wc = (w & 1) * 64;

  f32x4 acc[4][4];
  #pragma unroll
  for (int m = 0; m < 4; ++m)
    #pragma unroll
    for (int n = 0; n < 4; ++n) acc[m][n] = 0.0f;

  // staging: flat = t*256 + tid; row = flat>>2 (4 x 16B segs per 32-elem row)
  const int r0 = tid >> 2, seg = tid & 3;
  const ushort_t* gA0 = A  + (size_t)(brow + r0) * K      + seg * 8;
  const ushort_t* gA1 = A  + (size_t)(brow + r0 + 64) * K + seg * 8;
  const ushort_t* gB0 = BT + (size_t)(bcol + r0) * K      + seg * 8;
  const ushort_t* gB1 = BT + (size_t)(bcol + r0 + 64) * K + seg * 8;
  ushort_t* lA0 = &As[tid * 8];
  ushort_t* lA1 = &As[(256 + tid) * 8];
  ushort_t* lB0 = &Bs[tid * 8];
  ushort_t* lB1 = &Bs[(256 + tid) * 8];

  const int nk = K >> 5;
  for (int kt = 0; kt < nk; ++kt){
    const int ko = kt * 32;
    gload_lds16(gA0 + ko, lA0);
    gload_lds16(gA1 + ko, lA1);
    gload_lds16(gB0 + ko, lB0);
    gload_lds16(gB1 + ko, lB1);
    __syncthreads();   // drains vmcnt -> tiles visible

    bf16x8 af[4], bfr[4];
    #pragma unroll
    for (int m = 0; m < 4; ++m)
      af[m] = *(const bf16x8*)&As[(wr + m * 16 + l16) * 32 + lg * 8];
    #pragma unroll
    for (int n = 0; n < 4; ++n)
      bfr[n] = *(const bf16x8*)&Bs[(wc + n * 16 + l16) * 32 + lg * 8];
    #pragma unroll
    for (int m = 0; m < 4; ++m)
      #pragma unroll
      for (int n = 0; n < 4; ++n)
        acc[m][n] = mfma16(af[m], bfr[n], acc[m][n]);
    __syncthreads();   // protect tiles before next stage
  }

  #pragma unroll
  for (int n = 0; n < 4; ++n){
    const int col = bcol + wc + n * 16 + l16;
    const float bv = bias[col];
    #pragma unroll
    for (int m = 0; m < 4; ++m){
      const int row0 = brow + wr + m * 16 + lg * 4;
      f32x4 c = acc[m][n];
      #pragma unroll
      for (int r = 0; r < 4; ++r){
        float v = c[r] + bv;
        if (EPI == 2) v = v > 0.f ? v : 0.f;
        if (EPI == 1) outF[(size_t)(row0 + r) * N + col] = v;
        else          outB[(size_t)(row0 + r) * N + col] = f2b(v);
      }
    }
  }
}

// ---------------------------------------------------------------------------
// Flash attention. qkv[S][3072] bf16 (Q|K|V), vt[1024][4096] bf16 = V^T per
// head-dim row.  Output hcat[S][1024] bf16 = heads concatenated.
// Block = 4 waves x 32 q-rows = 128 q rows; KV tiles of 64, double-buffered.
// K/V tiles staged with XOR-swizzled global source (chunk ^= row&7) so
// ds_read_b128 B-fragments are conflict-free.
// ---------------------------------------------------------------------------
__global__ __launch_bounds__(256)
void flash_attn(const ushort_t* __restrict__ qkv, const ushort_t* __restrict__ vt,
                ushort_t* __restrict__ hcat)
{
  __shared__ __attribute__((aligned(16))) ushort_t Ks[2][64 * 64];
  __shared__ __attribute__((aligned(16))) ushort_t Vs[2][64 * 64];
  __shared__ __attribute__((aligned(16))) ushort_t Ps[4][32 * 64];
  const int tid = threadIdx.x, w = tid >> 6, lane = tid & 63;
  const int l16 = lane & 15, lg = lane >> 4, rsw = l16 & 7;
  const int h = blockIdx.y;
  const int q0 = blockIdx.x * 128 + w * 32;

  // Q fragments in registers: 2 m-frags x 2 k-chunks
  bf16x8 qf[2][2];
  #pragma unroll
  for (int m = 0; m < 2; ++m)
    #pragma unroll
    for (int kc = 0; kc < 2; ++kc)
      qf[m][kc] = *(const bf16x8*)&qkv[(size_t)(q0 + m * 16 + l16) * 3072 + h * 64 + kc * 32 + lg * 8];

  f32x4 o[2][4];
  float mrun[2][4], lpart[2][4];
  #pragma unroll
  for (int m = 0; m < 2; ++m){
    #pragma unroll
    for (int n = 0; n < 4; ++n) o[m][n] = 0.0f;
    #pragma unroll
    for (int r = 0; r < 4; ++r){ mrun[m][r] = -1e30f; lpart[m][r] = 0.f; }
  }

  // staging addresses (two 256-lane sweeps cover 64 rows x 8 chunks)
  const int sr0 = tid >> 3, sc = tid & 7;
  const int sr1 = 32 + sr0;
  const int cc0 = sc ^ (sr0 & 7), cc1 = sc ^ (sr1 & 7);
  const ushort_t* gk0 = qkv + (size_t)sr0 * 3072 + 1024 + h * 64 + cc0 * 8;
  const ushort_t* gk1 = qkv + (size_t)sr1 * 3072 + 1024 + h * 64 + cc1 * 8;
  const ushort_t* gv0 = vt + (size_t)(h * 64 + sr0) * 4096 + cc0 * 8;
  const ushort_t* gv1 = vt + (size_t)(h * 64 + sr1) * 4096 + cc1 * 8;

  auto stage = [&](int buf, int t){
    const int s0 = t * 64;
    gload_lds16(gk0 + (size_t)s0 * 3072, &Ks[buf][tid * 8]);
    gload_lds16(gk1 + (size_t)s0 * 3072, &Ks[buf][(256 + tid) * 8]);
    gload_lds16(gv0 + s0, &Vs[buf][tid * 8]);
    gload_lds16(gv1 + s0, &Vs[buf][(256 + tid) * 8]);
  };
  stage(0, 0);

  const float c2 = 0.18033688011112042f;  // log2(e)/8

  for (int t = 0; t < 64; ++t){
    const int buf = t & 1;
    __syncthreads();                 // staged tile t ready; tile t-1 readers done
    if (t < 63) stage(buf ^ 1, t + 1);

    // S = Q K^T  (raw dot products; scale folded into exp2 domain)
    f32x4 s[2][4];
    #pragma unroll
    for (int nf = 0; nf < 4; ++nf){
      const int krow = (nf * 16 + l16) * 64;
      bf16x8 kf0 = *(const bf16x8*)&Ks[buf][krow + ((lg     ^ rsw)) * 8];
      bf16x8 kf1 = *(const bf16x8*)&Ks[buf][krow + (((4+lg) ^ rsw)) * 8];
      #pragma unroll
      for (int m = 0; m < 2; ++m){
        f32x4 sv = 0.0f;
        sv = mfma16(qf[m][0], kf0, sv);
        sv = mfma16(qf[m][1], kf1, sv);
        s[m][nf] = sv;
      }
    }

    // online softmax (exp2 domain), P -> per-wave swizzled LDS
    #pragma unroll
    for (int m = 0; m < 2; ++m){
      float al[4];
      #pragma unroll
      for (int r = 0; r < 4; ++r){
        float vm = fmaxf(fmaxf(s[m][0][r], s[m][1][r]), fmaxf(s[m][2][r], s[m][3][r]));
        vm = fmaxf(vm, __shfl_xor(vm, 1));
        vm = fmaxf(vm, __shfl_xor(vm, 2));
        vm = fmaxf(vm, __shfl_xor(vm, 4));
        vm = fmaxf(vm, __shfl_xor(vm, 8));
        const float mt = vm * c2;
        const float mn = fmaxf(mrun[m][r], mt);
        al[r] = __builtin_amdgcn_exp2f(mrun[m][r] - mn);
        mrun[m][r] = mn;
      }
      #pragma unroll
      for (int nf = 0; nf < 4; ++nf)
        #pragma unroll
        for (int r = 0; r < 4; ++r)
          s[m][nf][r] = __builtin_amdgcn_exp2f(__builtin_fmaf(s[m][nf][r], c2, -mrun[m][r]));
      #pragma unroll
      for (int r = 0; r < 4; ++r){
        const float su = (s[m][0][r] + s[m][1][r]) + (s[m][2][r] + s[m][3][r]);
        lpart[m][r] = lpart[m][r] * al[r] + su;
      }
      #pragma unroll
      for (int n = 0; n < 4; ++n)
        #pragma unroll
        for (int r = 0; r < 4; ++r) o[m][n][r] *= al[r];
      #pragma unroll
      for (int r = 0; r < 4; ++r){
        const int q = m * 16 + lg * 4 + r;
        const int swz = (q & 7) << 4;
        char* base = (char*)&Ps[w][0] + q * 128;
        #pragma unroll
        for (int nf = 0; nf < 4; ++nf){
          const int kvb = (nf * 16 + l16) * 2;
          *(ushort_t*)(base + (kvb ^ swz)) = f2b(s[m][nf][r]);
        }
      }
    }
    asm volatile("s_waitcnt lgkmcnt(0)" ::: "memory");
    __builtin_amdgcn_sched_barrier(0);

    // O += P @ V  (V read from Vs = V^T tile, rows = d)
    #pragma unroll
    for (int kvc = 0; kvc < 2; ++kvc){
      bf16x8 pf[2];
      #pragma unroll
      for (int m = 0; m < 2; ++m){
        const int row = m * 16 + l16;
        const int off = (kvc * 64 + lg * 16) ^ ((row & 7) << 4);
        pf[m] = *(const bf16x8*)((const char*)&Ps[w][0] + row * 128 + off);
      }
      #pragma unroll
      for (int n = 0; n < 4; ++n){
        bf16x8 vf = *(const bf16x8*)&Vs[buf][(n * 16 + l16) * 64 + (((kvc * 4 + lg) ^ rsw)) * 8];
        #pragma unroll
        for (int m = 0; m < 2; ++m) o[m][n] = mfma16(pf[m], vf, o[m][n]);
      }
    }
  }

  // finalize: reduce l across the 16-lane column group, normalize, store
  #pragma unroll
  for (int m = 0; m < 2; ++m){
    float linv[4];
    #pragma unroll
    for (int r = 0; r < 4; ++r){
      float l = lpart[m][r];
      l += __shfl_xor(l, 1); l += __shfl_xor(l, 2);
      l += __shfl_xor(l, 4); l += __shfl_xor(l, 8);
      linv[r] = 1.f / l;
    }
    #pragma unroll
    for (int n = 0; n < 4; ++n)
      #pragma unroll
      for (int r = 0; r < 4; ++r){
        const size_t row = q0 + m * 16 + lg * 4 + r;
        hcat[row * 1024 + h * 64 + n * 16 + l16] = f2b(o[m][n][r] * linv[r]);
      }
  }
}

// ---------------------------------------------------------------------------
// Fused LayerNorm + residual: out = res + LN(in)*g + b  (row length 1024)
// ---------------------------------------------------------------------------
template<bool WB>
__global__ __launch_bounds__(256)
void ln_res(const float* __restrict__ in, const float* __restrict__ res,
            const float* __restrict__ g, const float* __restrict__ b,
            float* __restrict__ outF, ushort_t* __restrict__ outB)
{
  const int row = blockIdx.x, tid = threadIdx.x, w = tid >> 6, lane = tid & 63;
  const float4 v = ((const float4*)(in + (size_t)row * 1024))[tid];
  float s  = v.x + v.y + v.z + v.w;
  float s2 = v.x * v.x + v.y * v.y + v.z * v.z + v.w * v.w;
  #pragma unroll
  for (int off = 1; off < 64; off <<= 1){
    s  += __shfl_xor(s, off);
    s2 += __shfl_xor(s2, off);
  }
  __shared__ float red[8];
  if (lane == 0){ red[w] = s; red[4 + w] = s2; }
  __syncthreads();
  s  = red[0] + red[1] + red[2] + red[3];
  s2 = red[4] + red[5] + red[6] + red[7];
  const float mu   = s  * (1.f / 1024.f);
  const float var  = s2 * (1.f / 1024.f) - mu * mu;
  const float rstd = rsqrtf(var + 1e-5f);
  const float4 gv = ((const float4*)g)[tid];
  const float4 bv = ((const float4*)b)[tid];
  const float4 rv = ((const float4*)(res + (size_t)row * 1024))[tid];
  float4 y;
  y.x = rv.x + (v.x - mu) * rstd * gv.x + bv.x;
  y.y = rv.y + (v.y - mu) * rstd * gv.y + bv.y;
  y.z = rv.z + (v.z - mu) * rstd * gv.z + bv.z;
  y.w = rv.w + (v.w - mu) * rstd * gv.w + bv.w;
  ((float4*)(outF + (size_t)row * 1024))[tid] = y;
  if (WB){
    us4 u; u.x = f2b(y.x); u.y = f2b(y.y); u.z = f2b(y.z); u.w = f2b(y.w);
    ((us4*)(outB + (size_t)row * 1024))[tid] = u;
  }
}

// ---------------------------------------------------------------------------
// Transposes (f32 -> bf16, bf16 -> bf16) : out[c][r] = in[r][c]
// ---------------------------------------------------------------------------
__global__ void transpose_f2b(const float* __restrict__ in, int ldin,
                              ushort_t* __restrict__ out, int ldout)
{
  __shared__ float tile[32][33];
  const int bx = blockIdx.x * 32, by = blockIdx.y * 32;
  const int tx = threadIdx.x, ty = threadIdx.y;
  #pragma unroll
  for (int i = 0; i < 32; i += 8)
    tile[ty + i][tx] = in[(size_t)(by + ty + i) * ldin + bx + tx];
  __syncthreads();
  #pragma unroll
  for (int i = 0; i < 32; i += 8)
    out[(size_t)(bx + ty + i) * ldout + by + tx] = f2b(tile[tx][ty + i]);
}

__global__ void transpose_b2b(const ushort_t* __restrict__ in, int ldin,
                              ushort_t* __restrict__ out, int ldout)
{
  __shared__ ushort_t tile[32][34];
  const int bx = blockIdx.x * 32, by = blockIdx.y * 32;
  const int tx = threadIdx.x, ty = threadIdx.y;
  #pragma unroll
  for (int i = 0; i < 32; i += 8)
    tile[ty + i][tx] = in[(size_t)(by + ty + i) * ldin + bx + tx];
  __syncthreads();
  #pragma unroll
  for (int i = 0; i < 32; i += 8)
    out[(size_t)(bx + ty + i) * ldout + by + tx] = tile[tx][ty + i];
}

__global__ void cast_f2b_k(const float* __restrict__ in, ushort_t* __restrict__ out, int n4)
{
  for (int i = blockIdx.x * blockDim.x + threadIdx.x; i < n4; i += gridDim.x * blockDim.x){
    const float4 v = ((const float4*)in)[i];
    us4 u; u.x = f2b(v.x); u.y = f2b(v.y); u.z = f2b(v.z); u.w = f2b(v.w);
    ((us4*)out)[i] = u;
  }
}

__global__ void concat3(const float* __restrict__ a, const float* __restrict__ b,
                        const float* __restrict__ c, float* __restrict__ out)
{
  const int i = blockIdx.x * 256 + threadIdx.x;
  out[i] = i < 1024 ? a[i] : (i < 2048 ? b[i - 1024] : c[i - 2048]);
}

// ---------------------------------------------------------------------------
extern "C" void kernel_launch(void* const* d_in, const int* in_sizes, int n_in,
                              void* d_out, int out_size, void* d_ws, size_t ws_size,
                              hipStream_t stream)
{
  (void)in_sizes; (void)n_in; (void)out_size; (void)ws_size;
  const float* x   = (const float*)d_in[0];
  const float* Wq  = (const float*)d_in[1];
  const float* bq  = (const float*)d_in[2];
  const float* Wk  = (const float*)d_in[3];
  const float* bk  = (const float*)d_in[4];
  const float* Wv  = (const float*)d_in[5];
  const float* bv  = (const float*)d_in[6];
  const float* Wo  = (const float*)d_in[7];
  const float* bo  = (const float*)d_in[8];
  const float* g1  = (const float*)d_in[9];
  const float* b1  = (const float*)d_in[10];
  const float* Wf1 = (const float*)d_in[11];
  const float* bf1 = (const float*)d_in[12];
  const float* Wf2 = (const float*)d_in[13];
  const float* bf2 = (const float*)d_in[14];
  const float* g2  = (const float*)d_in[15];
  const float* b2  = (const float*)d_in[16];
  float* out = (float*)d_out;

  char* p = (char*)d_ws;
  auto alloc = [&](size_t bytes){ char* r = p; p += (bytes + 255) & ~(size_t)255; return r; };
  ushort_t* xb    = (ushort_t*)alloc((size_t)S_LEN * EMB * 2);
  ushort_t* wqkvT = (ushort_t*)alloc((size_t)3072 * 1024 * 2);
  ushort_t* wOT   = (ushort_t*)alloc((size_t)1024 * 1024 * 2);
  ushort_t* wf1T  = (ushort_t*)alloc((size_t)4096 * 1024 * 2);
  ushort_t* wf2T  = (ushort_t*)alloc((size_t)1024 * 4096 * 2);
  float*    bqkv  = (float*)alloc(3072 * 4);
  ushort_t* qkv   = (ushort_t*)alloc((size_t)4096 * 3072 * 2);   // 24 MB
  ushort_t* vtb   = (ushort_t*)alloc((size_t)1024 * 4096 * 2);   // 8 MB (contig after qkv)
  ushort_t* hcat  = (ushort_t*)alloc((size_t)4096 * 1024 * 2);
  float*    attnO = (float*)alloc((size_t)4096 * 1024 * 4);
  float*    y1    = (float*)alloc((size_t)4096 * 1024 * 4);
  ushort_t* y1b   = (ushort_t*)alloc((size_t)4096 * 1024 * 2);
  // aliases over dead buffers (qkv+vtb dead after flash; attnO dead after ln1)
  ushort_t* ff1 = qkv;          // 32 MB
  float*    ff2 = attnO;        // 16 MB

  const dim3 tb(32, 8);
  cast_f2b_k<<<2048, 256, 0, stream>>>(x, xb, S_LEN * EMB / 4);
  transpose_f2b<<<dim3(32, 32),  tb, 0, stream>>>(Wq, 1024, wqkvT,                 1024);
  transpose_f2b<<<dim3(32, 32),  tb, 0, stream>>>(Wk, 1024, wqkvT + 1024 * 1024,   1024);
  transpose_f2b<<<dim3(32, 32),  tb, 0, stream>>>(Wv, 1024, wqkvT + 2048 * 1024,   1024);
  transpose_f2b<<<dim3(32, 32),  tb, 0, stream>>>(Wo, 1024, wOT,  1024);
  transpose_f2b<<<dim3(128, 32), tb, 0, stream>>>(Wf1, 4096, wf1T, 1024);
  transpose_f2b<<<dim3(32, 128), tb, 0, stream>>>(Wf2, 1024, wf2T, 4096);
  concat3<<<12, 256, 0, stream>>>(bq, bk, bv, bqkv);

  // QKV = x @ [Wq|Wk|Wv] + b  -> bf16 [4096][3072]
  gemm_bt<0><<<dim3(3072 / 128, 4096 / 128), 256, 0, stream>>>(
      xb, wqkvT, 4096, 3072, 1024, bqkv, nullptr, qkv);
  // V^T  [1024 v-cols][4096 s]
  transpose_b2b<<<dim3(32, 128), tb, 0, stream>>>(qkv + 2048, 3072, vtb, 4096);
  // attention
  flash_attn<<<dim3(32, 16), 256, 0, stream>>>(qkv, vtb, hcat);
  // O-projection -> f32
  gemm_bt<1><<<dim3(1024 / 128, 4096 / 128), 256, 0, stream>>>(
      hcat, wOT, 4096, 1024, 1024, bo, attnO, nullptr);
  // y1 = x + LN(attnO)
  ln_res<true><<<4096, 256, 0, stream>>>(attnO, x, g1, b1, y1, y1b);
  // FF1 with ReLU -> bf16 (aliases qkv region)
  gemm_bt<2><<<dim3(4096 / 128, 4096 / 128), 256, 0, stream>>>(
      y1b, wf1T, 4096, 4096, 1024, bf1, nullptr, ff1);
  // FF2 -> f32 (aliases attnO region)
  gemm_bt<1><<<dim3(1024 / 128, 4096 / 128), 256, 0, stream>>>(
      ff1, wf2T, 4096, 1024, 4096, bf2, ff2, nullptr);
  // out = y1 + LN(ff2)
  ln_res<false><<<4096, 256, 0, stream>>>(ff2, y1, g2, b2, out, nullptr);
}

// Round 2
// 481.727 us; speedup vs baseline: 1.1951x; 1.1951x over previous
//
#include <hip/hip_runtime.h>

typedef unsigned short ushort_t;
typedef unsigned int uint32;
typedef __attribute__((ext_vector_type(8))) __bf16 bf16x8;
typedef __attribute__((ext_vector_type(4))) float f32x4;
typedef __attribute__((ext_vector_type(4))) unsigned short us4;

#define S_LEN 4096
#define EMB   1024
#define NH    16
#define HD    64
#define FFD   4096

__device__ __forceinline__ ushort_t f2b(float f){
  uint32 u = __builtin_bit_cast(uint32, f);
  u += 0x7fffu + ((u >> 16) & 1u);
  return (ushort_t)(u >> 16);
}

__device__ __forceinline__ void gload_lds16(const void* g, void* l){
  __builtin_amdgcn_global_load_lds((const __attribute__((address_space(1))) void*)g,
                                   (__attribute__((address_space(3))) void*)l,
                                   16, 0, 0);
}

__device__ __forceinline__ f32x4 mfma16(bf16x8 a, bf16x8 b, f32x4 c){
  return __builtin_amdgcn_mfma_f32_16x16x32_bf16(a, b, c, 0, 0, 0);
}

__device__ __forceinline__ float bperm_f(int srclane, float v){
  return __builtin_bit_cast(float,
      __builtin_amdgcn_ds_bpermute(srclane * 4, __builtin_bit_cast(int, v)));
}

// ---------------------------------------------------------------------------
// GEMM: C[M,N] = A[M,K] @ B + bias, with B given as BT[N,K] (row-major B^T).
// 128x128 tile, BK=32, 4 waves (2x2 of 64x64), m97 structure.
// EPI: 0 = bias -> bf16 out, 1 = bias -> f32 out, 2 = bias+relu -> bf16 out
// ---------------------------------------------------------------------------
template<int EPI>
__global__ __launch_bounds__(256)
void gemm_bt(const ushort_t* __restrict__ A, const ushort_t* __restrict__ BT,
             int M, int N, int K, const float* __restrict__ bias,
             float* __restrict__ outF, ushort_t* __restrict__ outB)
{
  __shared__ __attribute__((aligned(16))) ushort_t As[128 * 32];
  __shared__ __attribute__((aligned(16))) ushort_t Bs[128 * 32];
  const int tid = threadIdx.x;
  const int w = tid >> 6, lane = tid & 63, l16 = lane & 15, lg = lane >> 4;
  const int brow = blockIdx.y * 128, bcol = blockIdx.x * 128;
  const int wr = (w >> 1) * 64, wc = (w & 1) * 64;

  f32x4 acc[4][4];
  #pragma unroll
  for (int m = 0; m < 4; ++m)
    #pragma unroll
    for (int n = 0; n < 4; ++n) acc[m][n] = 0.0f;

  const int r0 = tid >> 2, seg = tid & 3;
  const ushort_t* gA0 = A  + (size_t)(brow + r0) * K      + seg * 8;
  const ushort_t* gA1 = A  + (size_t)(brow + r0 + 64) * K + seg * 8;
  const ushort_t* gB0 = BT + (size_t)(bcol + r0) * K      + seg * 8;
  const ushort_t* gB1 = BT + (size_t)(bcol + r0 + 64) * K + seg * 8;
  ushort_t* lA0 = &As[tid * 8];
  ushort_t* lA1 = &As[(256 + tid) * 8];
  ushort_t* lB0 = &Bs[tid * 8];
  ushort_t* lB1 = &Bs[(256 + tid) * 8];

  const int nk = K >> 5;
  for (int kt = 0; kt < nk; ++kt){
    const int ko = kt * 32;
    gload_lds16(gA0 + ko, lA0);
    gload_lds16(gA1 + ko, lA1);
    gload_lds16(gB0 + ko, lB0);
    gload_lds16(gB1 + ko, lB1);
    __syncthreads();

    bf16x8 af[4], bfr[4];
    #pragma unroll
    for (int m = 0; m < 4; ++m)
      af[m] = *(const bf16x8*)&As[(wr + m * 16 + l16) * 32 + lg * 8];
    #pragma unroll
    for (int n = 0; n < 4; ++n)
      bfr[n] = *(const bf16x8*)&Bs[(wc + n * 16 + l16) * 32 + lg * 8];
    #pragma unroll
    for (int m = 0; m < 4; ++m)
      #pragma unroll
      for (int n = 0; n < 4; ++n)
        acc[m][n] = mfma16(af[m], bfr[n], acc[m][n]);
    __syncthreads();
  }

  #pragma unroll
  for (int n = 0; n < 4; ++n){
    const int col = bcol + wc + n * 16 + l16;
    const float bv = bias[col];
    #pragma unroll
    for (int m = 0; m < 4; ++m){
      const int row0 = brow + wr + m * 16 + lg * 4;
      f32x4 c = acc[m][n];
      #pragma unroll
      for (int r = 0; r < 4; ++r){
        float v = c[r] + bv;
        if (EPI == 2) v = v > 0.f ? v : 0.f;
        if (EPI == 1) outF[(size_t)(row0 + r) * N + col] = v;
        else          outB[(size_t)(row0 + r) * N + col] = f2b(v);
      }
    }
  }
}

// ---------------------------------------------------------------------------
// Flash attention, swapped-QK^T + permuted K staging so P stays in-register.
//
// Block = 4 waves x 16 q-rows = 64 q rows; grid (64 qblocks, 16 heads).
// KV tiles of 64, double-buffered in LDS, column-XOR-swizzled sources.
//
// K rows are staged PERMUTED: LDS row j holds K[kv = perm(j)],
//   perm(j) = ((j>>2)&3)*8 + ((j>>4)&1)*4 + (j&3) + ((j>>5)&1)*32
// so after D = K·Q^T (col = q = lane&15, row = lg*4+r within nf-tile),
// lane (l16,lg)'s 16 scores are exactly kv = {kvc*32 + lg*8 + e},
// e = (nf&1)*4 + r, kvc = nf>>1 -- the PV A-fragment layout. P never
// leaves registers: no LDS round-trip, no cross-lane redistribution.
// ---------------------------------------------------------------------------
__global__ __launch_bounds__(256, 4)
void flash_attn(const ushort_t* __restrict__ qkv, const ushort_t* __restrict__ vt,
                ushort_t* __restrict__ hcat)
{
  __shared__ __attribute__((aligned(16))) ushort_t Ks[2][64 * 64];
  __shared__ __attribute__((aligned(16))) ushort_t Vs[2][64 * 64];
  const int tid = threadIdx.x, w = tid >> 6, lane = tid & 63;
  const int l16 = lane & 15, lg = lane >> 4, rsw = l16 & 7;
  const int h = blockIdx.y;
  const int q0 = blockIdx.x * 64 + w * 16;

  // Q fragments (B-operand: B[k=d][col=q=l16]): 2 k-chunks of 32
  bf16x8 qf[2];
  #pragma unroll
  for (int kc = 0; kc < 2; ++kc)
    qf[kc] = *(const bf16x8*)&qkv[(size_t)(q0 + l16) * 3072 + h * 64 + kc * 32 + lg * 8];

  f32x4 o[4];
  #pragma unroll
  for (int n = 0; n < 4; ++n) o[n] = 0.0f;
  float mrun = -1e30f, lpart = 0.f;

  // staging (two 256-lane sweeps = 64 rows x 8 col-chunks of 16B)
  const int sr0 = tid >> 3, sc = tid & 7;
  const int sr1 = 32 + sr0;
  const int cc0 = sc ^ (sr0 & 7), cc1 = sc ^ (sr1 & 7);
  // K rows permuted at the global source
  const int pr0 = ((sr0 >> 2) & 3) * 8 + ((sr0 >> 4) & 1) * 4 + (sr0 & 3) + ((sr0 >> 5) & 1) * 32;
  const int pr1 = ((sr1 >> 2) & 3) * 8 + ((sr1 >> 4) & 1) * 4 + (sr1 & 3) + ((sr1 >> 5) & 1) * 32;
  const ushort_t* gk0 = qkv + (size_t)pr0 * 3072 + 1024 + h * 64 + cc0 * 8;
  const ushort_t* gk1 = qkv + (size_t)pr1 * 3072 + 1024 + h * 64 + cc1 * 8;
  const ushort_t* gv0 = vt + (size_t)(h * 64 + sr0) * 4096 + cc0 * 8;
  const ushort_t* gv1 = vt + (size_t)(h * 64 + sr1) * 4096 + cc1 * 8;

  auto stage = [&](int buf, int t){
    const size_t s0 = (size_t)t * 64;
    gload_lds16(gk0 + s0 * 3072, &Ks[buf][tid * 8]);
    gload_lds16(gk1 + s0 * 3072, &Ks[buf][(256 + tid) * 8]);
    gload_lds16(gv0 + s0, &Vs[buf][tid * 8]);
    gload_lds16(gv1 + s0, &Vs[buf][(256 + tid) * 8]);
  };
  stage(0, 0);

  const float c2 = 0.18033688011112042f;  // log2(e)/8 (folds 1/sqrt(dk))

  for (int t = 0; t < 64; ++t){
    const int buf = t & 1;
    __syncthreads();                 // tile t staged; tile t-1 readers done
    if (t < 63) stage(buf ^ 1, t + 1);

    // S = K_perm · Q^T : s[nf] rows = permuted kv, col = q = l16
    f32x4 s[4];
    #pragma unroll
    for (int nf = 0; nf < 4; ++nf){
      const int krow = (nf * 16 + l16) * 64;
      bf16x8 kf0 = *(const bf16x8*)&Ks[buf][krow + ((lg     ^ rsw)) * 8];
      bf16x8 kf1 = *(const bf16x8*)&Ks[buf][krow + (((4+lg) ^ rsw)) * 8];
      f32x4 sv = 0.0f;
      sv = mfma16(kf0, qf[0], sv);
      sv = mfma16(kf1, qf[1], sv);
      s[nf] = sv;
    }

    // online softmax; all 16 of this lane's scores share q = l16
    float vm = s[0][0];
    #pragma unroll
    for (int nf = 0; nf < 4; ++nf)
      #pragma unroll
      for (int r = 0; r < 4; ++r) vm = fmaxf(vm, s[nf][r]);
    vm = fmaxf(vm, __shfl_xor(vm, 16));
    vm = fmaxf(vm, __shfl_xor(vm, 32));
    const float ms = vm * c2;

    if (__any(ms > mrun + 8.f)){       // defer-max: rescale only on real growth
      const float mn = fmaxf(mrun, ms);
      const float al = __builtin_amdgcn_exp2f(mrun - mn);
      mrun = mn;
      lpart *= al;
      float alo[4];
      #pragma unroll
      for (int r = 0; r < 4; ++r) alo[r] = bperm_f(lg * 4 + r, al);
      #pragma unroll
      for (int n = 0; n < 4; ++n)
        #pragma unroll
        for (int r = 0; r < 4; ++r) o[n][r] *= alo[r];
    }

    float lsum = 0.f;
    #pragma unroll
    for (int nf = 0; nf < 4; ++nf)
      #pragma unroll
      for (int r = 0; r < 4; ++r){
        const float p = __builtin_amdgcn_exp2f(__builtin_fmaf(s[nf][r], c2, -mrun));
        s[nf][r] = p;
        lsum += p;
      }
    lpart += lsum;

    // pack P -> PV A-fragments, fully in-lane thanks to the K row-perm
    bf16x8 pa[2];
    #pragma unroll
    for (int nf = 0; nf < 4; ++nf)
      #pragma unroll
      for (int r = 0; r < 4; ++r)
        pa[nf >> 1][(nf & 1) * 4 + r] = (__bf16)s[nf][r];

    // O += P @ V  (B-operand: V[kv][d], read from Vs = V^T tile)
    #pragma unroll
    for (int kvc = 0; kvc < 2; ++kvc)
      #pragma unroll
      for (int n = 0; n < 4; ++n){
        bf16x8 vf = *(const bf16x8*)&Vs[buf][(n * 16 + l16) * 64 + (((kvc * 4 + lg) ^ rsw)) * 8];
        o[n] = mfma16(pa[kvc], vf, o[n]);
      }
  }

  // finalize: total l per q (reduce across lg), redistribute to o-layout, store
  float lt = lpart;
  lt += __shfl_xor(lt, 16);
  lt += __shfl_xor(lt, 32);
  const float linv = 1.f / lt;       // valid for q = l16
  float linvo[4];
  #pragma unroll
  for (int r = 0; r < 4; ++r) linvo[r] = bperm_f(lg * 4 + r, linv);

  #pragma unroll
  for (int n = 0; n < 4; ++n)
    #pragma unroll
    for (int r = 0; r < 4; ++r){
      const size_t row = q0 + lg * 4 + r;
      hcat[row * 1024 + h * 64 + n * 16 + l16] = f2b(o[n][r] * linvo[r]);
    }
}

// ---------------------------------------------------------------------------
// Fused LayerNorm + residual: out = res + LN(in)*g + b  (row length 1024)
// ---------------------------------------------------------------------------
template<bool WB>
__global__ __launch_bounds__(256)
void ln_res(const float* __restrict__ in, const float* __restrict__ res,
            const float* __restrict__ g, const float* __restrict__ b,
            float* __restrict__ outF, ushort_t* __restrict__ outB)
{
  const int row = blockIdx.x, tid = threadIdx.x, w = tid >> 6, lane = tid & 63;
  const float4 v = ((const float4*)(in + (size_t)row * 1024))[tid];
  float s  = v.x + v.y + v.z + v.w;
  float s2 = v.x * v.x + v.y * v.y + v.z * v.z + v.w * v.w;
  #pragma unroll
  for (int off = 1; off < 64; off <<= 1){
    s  += __shfl_xor(s, off);
    s2 += __shfl_xor(s2, off);
  }
  __shared__ float red[8];
  if (lane == 0){ red[w] = s; red[4 + w] = s2; }
  __syncthreads();
  s  = red[0] + red[1] + red[2] + red[3];
  s2 = red[4] + red[5] + red[6] + red[7];
  const float mu   = s  * (1.f / 1024.f);
  const float var  = s2 * (1.f / 1024.f) - mu * mu;
  const float rstd = rsqrtf(var + 1e-5f);
  const float4 gv = ((const float4*)g)[tid];
  const float4 bv = ((const float4*)b)[tid];
  const float4 rv = ((const float4*)(res + (size_t)row * 1024))[tid];
  float4 y;
  y.x = rv.x + (v.x - mu) * rstd * gv.x + bv.x;
  y.y = rv.y + (v.y - mu) * rstd * gv.y + bv.y;
  y.z = rv.z + (v.z - mu) * rstd * gv.z + bv.z;
  y.w = rv.w + (v.w - mu) * rstd * gv.w + bv.w;
  ((float4*)(outF + (size_t)row * 1024))[tid] = y;
  if (WB){
    us4 u; u.x = f2b(y.x); u.y = f2b(y.y); u.z = f2b(y.z); u.w = f2b(y.w);
    ((us4*)(outB + (size_t)row * 1024))[tid] = u;
  }
}

// ---------------------------------------------------------------------------
// Transposes (f32 -> bf16, bf16 -> bf16) : out[c][r] = in[r][c]
// ---------------------------------------------------------------------------
__global__ void transpose_f2b(const float* __restrict__ in, int ldin,
                              ushort_t* __restrict__ out, int ldout)
{
  __shared__ float tile[32][33];
  const int bx = blockIdx.x * 32, by = blockIdx.y * 32;
  const int tx = threadIdx.x, ty = threadIdx.y;
  #pragma unroll
  for (int i = 0; i < 32; i += 8)
    tile[ty + i][tx] = in[(size_t)(by + ty + i) * ldin + bx + tx];
  __syncthreads();
  #pragma unroll
  for (int i = 0; i < 32; i += 8)
    out[(size_t)(bx + ty + i) * ldout + by + tx] = f2b(tile[tx][ty + i]);
}

__global__ void transpose_b2b(const ushort_t* __restrict__ in, int ldin,
                              ushort_t* __restrict__ out, int ldout)
{
  __shared__ ushort_t tile[32][34];
  const int bx = blockIdx.x * 32, by = blockIdx.y * 32;
  const int tx = threadIdx.x, ty = threadIdx.y;
  #pragma unroll
  for (int i = 0; i < 32; i += 8)
    tile[ty + i][tx] = in[(size_t)(by + ty + i) * ldin + bx + tx];
  __syncthreads();
  #pragma unroll
  for (int i = 0; i < 32; i += 8)
    out[(size_t)(bx + ty + i) * ldout + by + tx] = tile[tx][ty + i];
}

__global__ void cast_f2b_k(const float* __restrict__ in, ushort_t* __restrict__ out, int n4)
{
  for (int i = blockIdx.x * blockDim.x + threadIdx.x; i < n4; i += gridDim.x * blockDim.x){
    const float4 v = ((const float4*)in)[i];
    us4 u; u.x = f2b(v.x); u.y = f2b(v.y); u.z = f2b(v.z); u.w = f2b(v.w);
    ((us4*)out)[i] = u;
  }
}

__global__ void concat3(const float* __restrict__ a, const float* __restrict__ b,
                        const float* __restrict__ c, float* __restrict__ out)
{
  const int i = blockIdx.x * 256 + threadIdx.x;
  out[i] = i < 1024 ? a[i] : (i < 2048 ? b[i - 1024] : c[i - 2048]);
}

// ---------------------------------------------------------------------------
extern "C" void kernel_launch(void* const* d_in, const int* in_sizes, int n_in,
                              void* d_out, int out_size, void* d_ws, size_t ws_size,
                              hipStream_t stream)
{
  (void)in_sizes; (void)n_in; (void)out_size; (void)ws_size;
  const float* x   = (const float*)d_in[0];
  const float* Wq  = (const float*)d_in[1];
  const float* bq  = (const float*)d_in[2];
  const float* Wk  = (const float*)d_in[3];
  const float* bk  = (const float*)d_in[4];
  const float* Wv  = (const float*)d_in[5];
  const float* bv  = (const float*)d_in[6];
  const float* Wo  = (const float*)d_in[7];
  const float* bo  = (const float*)d_in[8];
  const float* g1  = (const float*)d_in[9];
  const float* b1  = (const float*)d_in[10];
  const float* Wf1 = (const float*)d_in[11];
  const float* bf1 = (const float*)d_in[12];
  const float* Wf2 = (const float*)d_in[13];
  const float* bf2 = (const float*)d_in[14];
  const float* g2  = (const float*)d_in[15];
  const float* b2  = (const float*)d_in[16];
  float* out = (float*)d_out;

  char* p = (char*)d_ws;
  auto alloc = [&](size_t bytes){ char* r = p; p += (bytes + 255) & ~(size_t)255; return r; };
  ushort_t* xb    = (ushort_t*)alloc((size_t)S_LEN * EMB * 2);
  ushort_t* wqkvT = (ushort_t*)alloc((size_t)3072 * 1024 * 2);
  ushort_t* wOT   = (ushort_t*)alloc((size_t)1024 * 1024 * 2);
  ushort_t* wf1T  = (ushort_t*)alloc((size_t)4096 * 1024 * 2);
  ushort_t* wf2T  = (ushort_t*)alloc((size_t)1024 * 4096 * 2);
  float*    bqkv  = (float*)alloc(3072 * 4);
  ushort_t* qkv   = (ushort_t*)alloc((size_t)4096 * 3072 * 2);   // 24 MB
  ushort_t* vtb   = (ushort_t*)alloc((size_t)1024 * 4096 * 2);   // 8 MB
  ushort_t* hcat  = (ushort_t*)alloc((size_t)4096 * 1024 * 2);
  float*    attnO = (float*)alloc((size_t)4096 * 1024 * 4);
  float*    y1    = (float*)alloc((size_t)4096 * 1024 * 4);
  ushort_t* y1b   = (ushort_t*)alloc((size_t)4096 * 1024 * 2);
  ushort_t* ff1 = qkv;          // alias (qkv dead after flash)
  float*    ff2 = attnO;        // alias (attnO dead after ln1)

  const dim3 tb(32, 8);
  cast_f2b_k<<<2048, 256, 0, stream>>>(x, xb, S_LEN * EMB / 4);
  transpose_f2b<<<dim3(32, 32),  tb, 0, stream>>>(Wq, 1024, wqkvT,                 1024);
  transpose_f2b<<<dim3(32, 32),  tb, 0, stream>>>(Wk, 1024, wqkvT + 1024 * 1024,   1024);
  transpose_f2b<<<dim3(32, 32),  tb, 0, stream>>>(Wv, 1024, wqkvT + 2048 * 1024,   1024);
  transpose_f2b<<<dim3(32, 32),  tb, 0, stream>>>(Wo, 1024, wOT,  1024);
  transpose_f2b<<<dim3(128, 32), tb, 0, stream>>>(Wf1, 4096, wf1T, 1024);
  transpose_f2b<<<dim3(32, 128), tb, 0, stream>>>(Wf2, 1024, wf2T, 4096);
  concat3<<<12, 256, 0, stream>>>(bq, bk, bv, bqkv);

  gemm_bt<0><<<dim3(3072 / 128, 4096 / 128), 256, 0, stream>>>(
      xb, wqkvT, 4096, 3072, 1024, bqkv, nullptr, qkv);
  transpose_b2b<<<dim3(32, 128), tb, 0, stream>>>(qkv + 2048, 3072, vtb, 4096);
  flash_attn<<<dim3(64, 16), 256, 0, stream>>>(qkv, vtb, hcat);
  gemm_bt<1><<<dim3(1024 / 128, 4096 / 128), 256, 0, stream>>>(
      hcat, wOT, 4096, 1024, 1024, bo, attnO, nullptr);
  ln_res<true><<<4096, 256, 0, stream>>>(attnO, x, g1, b1, y1, y1b);
  gemm_bt<2><<<dim3(4096 / 128, 4096 / 128), 256, 0, stream>>>(
      y1b, wf1T, 4096, 4096, 1024, bf1, nullptr, ff1);
  gemm_bt<1><<<dim3(1024 / 128, 4096 / 128), 256, 0, stream>>>(
      ff1, wf2T, 4096, 1024, 4096, bf2, ff2, nullptr);
  ln_res<false><<<4096, 256, 0, stream>>>(ff2, y1, g2, b2, out, nullptr);
}